// Round 18
// baseline (296.009 us; speedup 1.0000x reference)
//
#include <hip/hip_runtime.h>

// SNN block: cur = x @ W^T + b, then sequential leaky-integrate-fire scan.
// T=200, B=256, D_IN=512, D_H=512. BETA=0.9, THRESHOLD=1.0.
// d_out = [spk_rec | mem_rec] f32.
//
// Fast path (numerics validated R4-R17, absmax 0.03125 <= 0.26, fixed inputs):
//   1) convert_w: W -> fp16 hi + lo*2^12, PRE-SWIZZLED (tiny, 1MB)
//   2) MFMA split-GEMM (R11 version, ~150us wall over 7 structural variants):
//      fused in-register x split, dbuf one-barrier, XCD-chunked swizzle.
//   3) scan R18: ONE chain/thread (512 blocks = 8 waves/CU, 2x the TLP of the
//      float2 version's 4 waves/CU) + nontemporal stores (R17, -11us). With
//      write-allocate pressure gone, read latency is the limiter -> more
//      resident waves. Per-element arithmetic identical (contract off).
//   4) exact_cur_g (R14 lane map: 8t x 8slot per wave) + rescan_g (R16's
//      block-per-b fusion measured SLOWER; split tail is best).
// Slow path (ws too small): R3's verified f32 GEMM + scan (absmax 0.0).

#define T_STEPS 200
#define BATCH   256
#define DIN     512
#define DH      512
#define MARGIN  1e-4f
#define LISTCAP 510
#define TQ2     32      // timesteps per exact_cur_g block (grid.y = 7)

constexpr int    MM  = T_STEPS * BATCH;           // 51200
constexpr int    BH  = BATCH * DH;                // 131072
constexpr size_t TBH = (size_t)T_STEPS * BH;      // 26,214,400

typedef _Float16 f16x8 __attribute__((ext_vector_type(8)));
typedef _Float16 f16x4 __attribute__((ext_vector_type(4)));
typedef float    f32x4 __attribute__((ext_vector_type(4)));

// ---- workspace layout (bytes); end <= 106,429,440 (R4-R17-certified) ----
constexpr size_t OFF_WH    = 104857600;
constexpr size_t OFF_WL    = 105381888;      // +512*512*2
constexpr size_t OFF_CNTB  = 105906176;      // 256 * u32
constexpr size_t OFF_LISTB = 105907200;      // 256 * LISTCAP * u32
constexpr size_t WS_REQ    = OFF_LISTB + (size_t)256 * LISTCAP * 4;  // 106,429,440
// cur_ex staging uses [0, 104,857,600) — untouched by the GEMM path.

// ============ Pass 1: split-convert W only, pre-swizzled ====================
// Element (row, k) stored at row*512 + (k&~31) + ((((k>>3)&3)^((row>>1)&3))<<3) + (k&7).
__global__ __launch_bounds__(256) void convert_w(const float* __restrict__ W,
                                                 _Float16* __restrict__ wh,
                                                 _Float16* __restrict__ wl) {
    const int q = blockIdx.x * 256 + threadIdx.x;   // 0..65535 float4s
    const float4 v = reinterpret_cast<const float4*>(W)[q];
    f16x4 h, l;
    h[0] = (_Float16)v.x; l[0] = (_Float16)((v.x - (float)h[0]) * 4096.0f);
    h[1] = (_Float16)v.y; l[1] = (_Float16)((v.y - (float)h[1]) * 4096.0f);
    h[2] = (_Float16)v.z; l[2] = (_Float16)((v.z - (float)h[2]) * 4096.0f);
    h[3] = (_Float16)v.w; l[3] = (_Float16)((v.w - (float)h[3]) * 4096.0f);
    const int row = q >> 7;                  // W-row (h index)
    const int k   = (q & 127) * 4;
    const int osw = ((k >> 3) & 3) ^ ((row >> 1) & 3);
    const long long dst = (long long)row * 512 + (k & ~31) + (osw << 3) + (k & 7);
    *reinterpret_cast<f16x4*>(wh + dst) = h;
    *reinterpret_cast<f16x4*>(wl + dst) = l;
}

// ================= Pass 2: MFMA split GEMM (R11 version) ====================
__device__ __forceinline__ void gload16(const void* g, void* l) {
    __builtin_amdgcn_global_load_lds(
        (const __attribute__((address_space(1))) void*)g,
        (__attribute__((address_space(3))) void*)l, 16, 0, 0);
}

__global__ __launch_bounds__(256) void gemm_split(const float* __restrict__ x,
                                                  const _Float16* __restrict__ wh,
                                                  const _Float16* __restrict__ wl,
                                                  const float* __restrict__ bias,
                                                  float* __restrict__ C) {
    __shared__ _Float16 ldsA[2][2][128][32];  // [buf][hi/lo][row][k]  32 KiB
    __shared__ _Float16 ldsB[2][2][64][32];   // [buf][hi/lo][row][k]  16 KiB

    const int tid  = threadIdx.x;
    const int w    = tid >> 6;
    const int lane = tid & 63;
    const int wr   = (w >> 1) * 64;            // wave rows: 0 or 64
    const int wc   = (w & 1) * 32;             // wave cols: 0 or 32
    const int lrow = lane & 15;
    // swizzled k-octet offset: physical octet = logical(lane>>4) ^ ((lrow>>1)&3)
    const int gsw  = (((lane >> 4) ^ ((lrow >> 1) & 3)) * 8);

    // XCD-chunked bijective swizzle: 3200 blocks = 8 XCDs x 400.
    const int orig = (blockIdx.x & 7) * 400 + (blockIdx.x >> 3);
    const int row0 = (orig >> 3) * 128;
    const int col0 = (orig & 7) * 64;

    // staging indices
    const int sr = tid >> 2;          // 0..63
    const int so = tid & 3;           // k-octet 0..3
    const int kq = so * 8;

    f32x4 acc_hh[4][2] = {};
    f32x4 acc_cr[4][2] = {};

    // A: f32 global -> in-register split (identical formula to convert_w) ->
    // swizzled ds_write_b128. B: pre-swizzled fp16 via linear global_load_lds.
    auto stage = [&](int bf, int k0) {
#pragma unroll
        for (int p = 0; p < 2; ++p) {
            const int r = sr + p * 64;
            const float* src = &x[(size_t)(row0 + r) * DIN + k0 + kq];
            const float4 v0 = *reinterpret_cast<const float4*>(src);
            const float4 v1 = *reinterpret_cast<const float4*>(src + 4);
            f16x8 h, l;
            h[0] = (_Float16)v0.x; l[0] = (_Float16)((v0.x - (float)h[0]) * 4096.0f);
            h[1] = (_Float16)v0.y; l[1] = (_Float16)((v0.y - (float)h[1]) * 4096.0f);
            h[2] = (_Float16)v0.z; l[2] = (_Float16)((v0.z - (float)h[2]) * 4096.0f);
            h[3] = (_Float16)v0.w; l[3] = (_Float16)((v0.w - (float)h[3]) * 4096.0f);
            h[4] = (_Float16)v1.x; l[4] = (_Float16)((v1.x - (float)h[4]) * 4096.0f);
            h[5] = (_Float16)v1.y; l[5] = (_Float16)((v1.y - (float)h[5]) * 4096.0f);
            h[6] = (_Float16)v1.z; l[6] = (_Float16)((v1.z - (float)h[6]) * 4096.0f);
            h[7] = (_Float16)v1.w; l[7] = (_Float16)((v1.w - (float)h[7]) * 4096.0f);
            const int po = (so ^ ((r >> 1) & 3)) * 8;   // same swizzle as reads
            *reinterpret_cast<f16x8*>(&ldsA[bf][0][r][po]) = h;
            *reinterpret_cast<f16x8*>(&ldsA[bf][1][r][po]) = l;
        }
        gload16(wh + (size_t)(col0 + sr) * DIN + k0 + kq, &ldsB[bf][0][sr][kq]);
        gload16(wl + (size_t)(col0 + sr) * DIN + k0 + kq, &ldsB[bf][1][sr][kq]);
    };

    stage(0, 0);

    int buf = 0;
    for (int kt = 0; kt < 16; ++kt) {
        __syncthreads();   // stage(kt) resident (vm+lgkm); prior reads done
        if (kt < 15) stage(buf ^ 1, (kt + 1) * 32);

        f16x8 ah[4], al[4];
#pragma unroll
        for (int fr = 0; fr < 4; ++fr) {
            ah[fr] = *reinterpret_cast<const f16x8*>(&ldsA[buf][0][wr + fr * 16 + lrow][gsw]);
            al[fr] = *reinterpret_cast<const f16x8*>(&ldsA[buf][1][wr + fr * 16 + lrow][gsw]);
        }
#pragma unroll
        for (int fc = 0; fc < 2; ++fc) {
            const f16x8 bh = *reinterpret_cast<const f16x8*>(&ldsB[buf][0][wc + fc * 16 + lrow][gsw]);
            const f16x8 bl = *reinterpret_cast<const f16x8*>(&ldsB[buf][1][wc + fc * 16 + lrow][gsw]);
#pragma unroll
            for (int fr = 0; fr < 4; ++fr) {
                acc_hh[fr][fc] = __builtin_amdgcn_mfma_f32_16x16x32_f16(ah[fr], bh, acc_hh[fr][fc], 0, 0, 0);
                acc_cr[fr][fc] = __builtin_amdgcn_mfma_f32_16x16x32_f16(ah[fr], bl, acc_cr[fr][fc], 0, 0, 0);
                acc_cr[fr][fc] = __builtin_amdgcn_mfma_f32_16x16x32_f16(al[fr], bh, acc_cr[fr][fc], 0, 0, 0);
            }
        }
        buf ^= 1;
    }

    // epilogue: cur = hh + 2^-12 * cross + bias (C/D: col=lane&15, row=(lane>>4)*4+reg)
#pragma unroll
    for (int fr = 0; fr < 4; ++fr)
#pragma unroll
        for (int fc = 0; fc < 2; ++fc) {
            const int col = col0 + wc + fc * 16 + lrow;
            const float bv = bias[col];
#pragma unroll
            for (int r = 0; r < 4; ++r) {
                const int row = row0 + wr + fr * 16 + (lane >> 4) * 4 + r;
                C[(size_t)row * DH + col] =
                    acc_hh[fr][fc][r] + acc_cr[fr][fc][r] * (1.0f / 4096.0f) + bv;
            }
        }
}

// ========== Pass 3: scan + flag, 1 chain/thread + nt stores =================
// Per-element step arithmetic identical to R4-R17 (contract off, same order).
__global__ __launch_bounds__(256) void snn_scan_flag(float* __restrict__ buf,
                                                     float* __restrict__ spk,
                                                     unsigned* __restrict__ cnt_b,
                                                     unsigned* __restrict__ list_b) {
#pragma clang fp contract(off)
    const int i = blockIdx.x * 256 + threadIdx.x;
    float c[8];
#pragma unroll
    for (int t = 0; t < 8; ++t) c[t] = buf[(size_t)t * BH + i];
    float mem = 0.0f;
    bool flag = false;
#pragma unroll 8
    for (int t = 0; t < T_STEPS - 8; ++t) {
        const float cur = c[t & 7];
        c[t & 7] = buf[(size_t)(t + 8) * BH + i];   // 8 loads in flight
        const float reset = (mem > 1.0f) ? 1.0f : 0.0f;
        float tmp = 0.9f * mem;
        tmp = tmp + cur;
        mem = tmp - reset;
        flag = flag || (fabsf(mem - 1.0f) < MARGIN);
        const float s = (mem > 1.0f) ? 1.0f : 0.0f;
        __builtin_nontemporal_store(s, &spk[(size_t)t * BH + i]);
        __builtin_nontemporal_store(mem, &buf[(size_t)t * BH + i]);
    }
#pragma unroll
    for (int t = T_STEPS - 8; t < T_STEPS; ++t) {
        const float cur = c[t & 7];
        const float reset = (mem > 1.0f) ? 1.0f : 0.0f;
        float tmp = 0.9f * mem;
        tmp = tmp + cur;
        mem = tmp - reset;
        flag = flag || (fabsf(mem - 1.0f) < MARGIN);
        const float s = (mem > 1.0f) ? 1.0f : 0.0f;
        __builtin_nontemporal_store(s, &spk[(size_t)t * BH + i]);
        __builtin_nontemporal_store(mem, &buf[(size_t)t * BH + i]);
    }
    if (flag) {
        const int b = i >> 9;         // i = b*512 + h
        const int h = i & 511;
        const unsigned slot = atomicAdd(&cnt_b[b], 1u);
        if (slot < (unsigned)LISTCAP) list_b[(size_t)b * LISTCAP + slot] = (unsigned)h;
    }
}

// ======== Pass 4: exact dot recompute — R14 (8 t x 8 slots per wave) ========
__global__ __launch_bounds__(256) void exact_cur_g(const float* __restrict__ x,
                                                   const float* __restrict__ W,
                                                   const float* __restrict__ bias,
                                                   const unsigned* __restrict__ cnt_b,
                                                   const unsigned* __restrict__ list_b,
                                                   float* __restrict__ cur_ex) {
    const int b = blockIdx.x;
    unsigned n = cnt_b[b];
    if (n == 0) return;
    const bool all = (n > (unsigned)LISTCAP);
    if (all) n = 512;

    const int jl = (int)(threadIdx.x & 7);        // slot within group of 8
    const int tl = (int)(threadIdx.x >> 3);       // 0..31
    const int t  = blockIdx.y * TQ2 + tl;
    if (t >= T_STEPS) return;                     // no barriers in kernel
    const float4* xr = reinterpret_cast<const float4*>(x + ((size_t)t * BATCH + b) * DIN);

    for (unsigned base = 0; base < n; base += 8) {
        const unsigned slot = base + (unsigned)jl;
        if (slot >= n) break;
        const int h = all ? (int)slot : (int)list_b[(size_t)b * LISTCAP + slot];
        const float4* wr = reinterpret_cast<const float4*>(W + (size_t)h * DIN);
        float acc = 0.0f;
#pragma unroll 8
        for (int kk = 0; kk < DIN / 4; ++kk) {   // ascending-k fma chain == np
            const float4 a = xr[kk];
            const float4 ww = wr[kk];
            acc = fmaf(a.x, ww.x, acc);
            acc = fmaf(a.y, ww.y, acc);
            acc = fmaf(a.z, ww.z, acc);
            acc = fmaf(a.w, ww.w, acc);
        }
        cur_ex[((size_t)b * 512 + slot) * T_STEPS + t] = acc + bias[h];
    }
}

// ======== Pass 5: exact rescan, one THREAD per flagged pair =================
__global__ __launch_bounds__(256) void rescan_g(const float* __restrict__ cur_ex,
                                                const unsigned* __restrict__ cnt_b,
                                                const unsigned* __restrict__ list_b,
                                                float* __restrict__ buf,
                                                float* __restrict__ spk) {
#pragma clang fp contract(off)
    const int b = blockIdx.x;
    unsigned n = cnt_b[b];
    if (n == 0) return;
    const bool all = (n > (unsigned)LISTCAP);
    if (all) n = 512;

    for (unsigned slot = threadIdx.x; slot < n; slot += 256) {
        const int h = all ? (int)slot : (int)list_b[(size_t)b * LISTCAP + slot];
        const unsigned i = ((unsigned)b << 9) | (unsigned)h;
        const float* cr = cur_ex + ((size_t)b * 512 + slot) * T_STEPS;
        float mem = 0.0f;
        for (int t = 0; t < T_STEPS; ++t) {
            const float c = cr[t];
            const float reset = (mem > 1.0f) ? 1.0f : 0.0f;
            float tmp = 0.9f * mem;
            tmp = tmp + c;
            mem = tmp - reset;
            const float s = (mem > 1.0f) ? 1.0f : 0.0f;
            spk[(size_t)t * BH + i] = s;
            buf[(size_t)t * BH + i] = mem;
        }
    }
}

// ================= legacy f32 path (R3, verified absmax 0.0) ================
#define BKf 32
#define LPADf 132
__global__ __launch_bounds__(256, 3) void gemm_nt_f32(const float* __restrict__ A,
                                                      const float* __restrict__ W,
                                                      const float* __restrict__ bias,
                                                      float* __restrict__ C) {
    __shared__ float As[BKf][LPADf];
    __shared__ float Bs[BKf][LPADf];
    const int tid = threadIdx.x;
    const int tx = tid & 15, ty = tid >> 4;
    const int row0 = blockIdx.x * 128, col0 = blockIdx.y * 128;
    const int lr = tid >> 2, lk = (tid & 3) * 4;
    const float* Abase = A + (size_t)(row0 + lr) * DIN + lk;
    const float* Bbase = W + (size_t)(col0 + lr) * DIN + lk;
    float acc[8][8] = {};
    float4 ra00, ra01, ra10, ra11, rb00, rb01, rb10, rb11;
#define LOADREG(k0)                                                        \
    do {                                                                   \
        ra00 = *reinterpret_cast<const float4*>(Abase + (k0));             \
        ra01 = *reinterpret_cast<const float4*>(Abase + (k0) + 16);        \
        ra10 = *reinterpret_cast<const float4*>(Abase + 64 * DIN + (k0));  \
        ra11 = *reinterpret_cast<const float4*>(Abase + 64 * DIN + (k0) + 16); \
        rb00 = *reinterpret_cast<const float4*>(Bbase + (k0));             \
        rb01 = *reinterpret_cast<const float4*>(Bbase + (k0) + 16);        \
        rb10 = *reinterpret_cast<const float4*>(Bbase + 64 * DIN + (k0));  \
        rb11 = *reinterpret_cast<const float4*>(Bbase + 64 * DIN + (k0) + 16); \
    } while (0)
#define STOREV(arr, kb, r, v)                                              \
    do { arr[(kb)+0][r]=(v).x; arr[(kb)+1][r]=(v).y; arr[(kb)+2][r]=(v).z; arr[(kb)+3][r]=(v).w; } while (0)
    LOADREG(0);
    for (int kt = 0; kt < DIN / BKf; ++kt) {
        __syncthreads();
        STOREV(As, lk, lr, ra00); STOREV(As, 16 + lk, lr, ra01);
        STOREV(As, lk, lr + 64, ra10); STOREV(As, 16 + lk, lr + 64, ra11);
        STOREV(Bs, lk, lr, rb00); STOREV(Bs, 16 + lk, lr, rb01);
        STOREV(Bs, lk, lr + 64, rb10); STOREV(Bs, 16 + lk, lr + 64, rb11);
        __syncthreads();
        if (kt + 1 < DIN / BKf) LOADREG((kt + 1) * BKf);
#pragma unroll 8
        for (int k = 0; k < BKf; ++k) {
            float a[8], b[8];
            const float4 t0 = *reinterpret_cast<const float4*>(&As[k][ty * 8 + 0]);
            const float4 t1 = *reinterpret_cast<const float4*>(&As[k][ty * 8 + 4]);
            a[0]=t0.x; a[1]=t0.y; a[2]=t0.z; a[3]=t0.w;
            a[4]=t1.x; a[5]=t1.y; a[6]=t1.z; a[7]=t1.w;
            const float4 u0 = *reinterpret_cast<const float4*>(&Bs[k][tx * 4]);
            const float4 u1 = *reinterpret_cast<const float4*>(&Bs[k][64 + tx * 4]);
            b[0]=u0.x; b[1]=u0.y; b[2]=u0.z; b[3]=u0.w;
            b[4]=u1.x; b[5]=u1.y; b[6]=u1.z; b[7]=u1.w;
#pragma unroll
            for (int i = 0; i < 8; ++i)
#pragma unroll
                for (int j = 0; j < 8; ++j) acc[i][j] += a[i] * b[j];
        }
    }
#pragma unroll
    for (int i = 0; i < 8; ++i) {
        const int r = row0 + ty * 8 + i, c0 = col0 + tx * 4, c1 = col0 + 64 + tx * 4;
        float4 o0, o1;
        o0.x = acc[i][0] + bias[c0 + 0]; o0.y = acc[i][1] + bias[c0 + 1];
        o0.z = acc[i][2] + bias[c0 + 2]; o0.w = acc[i][3] + bias[c0 + 3];
        o1.x = acc[i][4] + bias[c1 + 0]; o1.y = acc[i][5] + bias[c1 + 1];
        o1.z = acc[i][6] + bias[c1 + 2]; o1.w = acc[i][7] + bias[c1 + 3];
        *reinterpret_cast<float4*>(&C[(size_t)r * DH + c0]) = o0;
        *reinterpret_cast<float4*>(&C[(size_t)r * DH + c1]) = o1;
    }
#undef LOADREG
#undef STOREV
}

__global__ __launch_bounds__(256) void snn_scan(float* buf, float* spk) {
    const int i = blockIdx.x * 256 + threadIdx.x;
    float mem = 0.0f;
    float c = buf[i];
    for (int t = 0; t < T_STEPS; ++t) {
        float cn = (t + 1 < T_STEPS) ? buf[(size_t)(t + 1) * BH + i] : 0.0f;
        const float reset = (mem > 1.0f) ? 1.0f : 0.0f;
        mem = 0.9f * mem + c - reset;
        const float s = (mem > 1.0f) ? 1.0f : 0.0f;
        spk[(size_t)t * BH + i] = s;
        buf[(size_t)t * BH + i] = mem;
        c = cn;
    }
}

// ============================================================================
extern "C" void kernel_launch(void* const* d_in, const int* in_sizes, int n_in,
                              void* d_out, int out_size, void* d_ws, size_t ws_size,
                              hipStream_t stream) {
    const float* x    = (const float*)d_in[0];
    const float* W    = (const float*)d_in[1];
    const float* bias = (const float*)d_in[2];
    float* out = (float*)d_out;
    float* spk = out;
    float* mem = out + TBH;   // holds cur between GEMM and scan

    if (ws_size >= WS_REQ) {
        char* ws = (char*)d_ws;
        _Float16* wh = (_Float16*)(ws + OFF_WH);
        _Float16* wl = (_Float16*)(ws + OFF_WL);
        unsigned* cnt_b  = (unsigned*)(ws + OFF_CNTB);
        unsigned* list_b = (unsigned*)(ws + OFF_LISTB);
        float*    cur_ex = (float*)ws;   // [0, 104.9MB): free until Pass 4

        (void)hipMemsetAsync(cnt_b, 0, 1024, stream);
        convert_w<<<256, 256, 0, stream>>>(W, wh, wl);
        gemm_split<<<3200, 256, 0, stream>>>(x, wh, wl, bias, mem);
        snn_scan_flag<<<BH / 256, 256, 0, stream>>>(mem, spk, cnt_b, list_b);
        dim3 egrid(BATCH, (T_STEPS + TQ2 - 1) / TQ2);  // 256 x 7
        exact_cur_g<<<egrid, 256, 0, stream>>>(x, W, bias, cnt_b, list_b, cur_ex);
        rescan_g<<<BATCH, 256, 0, stream>>>(cur_ex, cnt_b, list_b, mem, spk);
    } else {
        dim3 grid(MM / 128, DH / 128);
        gemm_nt_f32<<<grid, 256, 0, stream>>>(x, W, bias, mem);
        snn_scan<<<BH / 256, 256, 0, stream>>>(mem, spk);
    }
}

// Round 19
// 280.274 us; speedup vs baseline: 1.0561x; 1.0561x over previous
//
#include <hip/hip_runtime.h>

// SNN block: cur = x @ W^T + b, then sequential leaky-integrate-fire scan.
// T=200, B=256, D_IN=512, D_H=512. BETA=0.9, THRESHOLD=1.0.
// d_out = [spk_rec | mem_rec] f32.
//
// Fast path (numerics validated R4-R18, absmax 0.03125 <= 0.26, fixed inputs):
//   1) convert_w: W -> fp16 hi + lo*2^12, PRE-SWIZZLED (tiny, 1MB)
//   2) MFMA split-GEMM R19: 512 threads (8 waves), 128x128 tile, SAME 64x32
//      per-wave sub-tile as R10-R18 (register-safe: 64 AGPR acc). 16 waves/CU
//      (vs 12), B DMA amortized 2x, x refetch halved (4 col-blocks/panel vs
//      8). Per-output MFMA chain and all arithmetic unchanged -> bit-exact.
//      History: 8 prior variants at 145-160us; this attacks the remaining
//      latency exposure via TLP, not schedule.
//   3) scan: 1 chain/thread + nontemporal stores (R17/R18 plateau ~65us).
//   4) exact_cur_g (R14 lane map) + rescan_g (best-measured split tail).
// Slow path (ws too small): R3's verified f32 GEMM + scan (absmax 0.0).

#define T_STEPS 200
#define BATCH   256
#define DIN     512
#define DH      512
#define MARGIN  1e-4f
#define LISTCAP 510
#define TQ2     32      // timesteps per exact_cur_g block (grid.y = 7)

constexpr int    MM  = T_STEPS * BATCH;           // 51200
constexpr int    BH  = BATCH * DH;                // 131072
constexpr size_t TBH = (size_t)T_STEPS * BH;      // 26,214,400

typedef _Float16 f16x8 __attribute__((ext_vector_type(8)));
typedef _Float16 f16x4 __attribute__((ext_vector_type(4)));
typedef float    f32x4 __attribute__((ext_vector_type(4)));

// ---- workspace layout (bytes); end <= 106,429,440 (R4-R18-certified) ----
constexpr size_t OFF_WH    = 104857600;
constexpr size_t OFF_WL    = 105381888;      // +512*512*2
constexpr size_t OFF_CNTB  = 105906176;      // 256 * u32
constexpr size_t OFF_LISTB = 105907200;      // 256 * LISTCAP * u32
constexpr size_t WS_REQ    = OFF_LISTB + (size_t)256 * LISTCAP * 4;  // 106,429,440
// cur_ex staging uses [0, 104,857,600) — untouched by the GEMM path.

// ============ Pass 1: split-convert W only, pre-swizzled ====================
// Element (row, k) stored at row*512 + (k&~31) + ((((k>>3)&3)^((row>>1)&3))<<3) + (k&7).
__global__ __launch_bounds__(256) void convert_w(const float* __restrict__ W,
                                                 _Float16* __restrict__ wh,
                                                 _Float16* __restrict__ wl) {
    const int q = blockIdx.x * 256 + threadIdx.x;   // 0..65535 float4s
    const float4 v = reinterpret_cast<const float4*>(W)[q];
    f16x4 h, l;
    h[0] = (_Float16)v.x; l[0] = (_Float16)((v.x - (float)h[0]) * 4096.0f);
    h[1] = (_Float16)v.y; l[1] = (_Float16)((v.y - (float)h[1]) * 4096.0f);
    h[2] = (_Float16)v.z; l[2] = (_Float16)((v.z - (float)h[2]) * 4096.0f);
    h[3] = (_Float16)v.w; l[3] = (_Float16)((v.w - (float)h[3]) * 4096.0f);
    const int row = q >> 7;                  // W-row (h index)
    const int k   = (q & 127) * 4;
    const int osw = ((k >> 3) & 3) ^ ((row >> 1) & 3);
    const long long dst = (long long)row * 512 + (k & ~31) + (osw << 3) + (k & 7);
    *reinterpret_cast<f16x4*>(wh + dst) = h;
    *reinterpret_cast<f16x4*>(wl + dst) = l;
}

// ================= Pass 2: MFMA split GEMM (512 thr, 128x128) ===============
__device__ __forceinline__ void gload16(const void* g, void* l) {
    __builtin_amdgcn_global_load_lds(
        (const __attribute__((address_space(1))) void*)g,
        (__attribute__((address_space(3))) void*)l, 16, 0, 0);
}

__global__ __launch_bounds__(512) void gemm_split(const float* __restrict__ x,
                                                  const _Float16* __restrict__ wh,
                                                  const _Float16* __restrict__ wl,
                                                  const float* __restrict__ bias,
                                                  float* __restrict__ C) {
    __shared__ _Float16 ldsA[2][2][128][32];  // [buf][hi/lo][row][k]  32 KiB
    __shared__ _Float16 ldsB[2][2][128][32];  // [buf][hi/lo][row][k]  32 KiB

    const int tid  = threadIdx.x;
    const int w    = tid >> 6;                 // wave 0..7
    const int lane = tid & 63;
    const int wr   = (w >> 2) * 64;            // wave rows: 0 or 64
    const int wc   = (w & 3) * 32;             // wave cols: 0,32,64,96
    const int lrow = lane & 15;
    // swizzled k-octet offset: physical octet = logical(lane>>4) ^ ((lrow>>1)&3)
    const int gsw  = (((lane >> 4) ^ ((lrow >> 1) & 3)) * 8);

    // XCD-chunked bijective swizzle: 1600 blocks = 8 XCDs x 200.
    const int orig = (blockIdx.x & 7) * 200 + (blockIdx.x >> 3);
    const int row0 = (orig >> 2) * 128;        // 400 row panels
    const int col0 = (orig & 3) * 128;         // 4 col blocks

    // staging indices: 512 threads cover 128 rows x 4 k-octets (1 row each)
    const int sr = tid >> 2;          // 0..127
    const int so = tid & 3;           // k-octet 0..3
    const int kq = so * 8;
    const int po = (so ^ ((sr >> 1) & 3)) * 8;   // swizzled octet for row sr

    f32x4 acc_hh[4][2] = {};
    f32x4 acc_cr[4][2] = {};

    // A: f32 global -> in-register split (identical formula) -> swizzled
    // ds_write_b128. B: pre-swizzled fp16 via linear global_load_lds.
    auto stage = [&](int bf, int k0) {
        const float* src = &x[(size_t)(row0 + sr) * DIN + k0 + kq];
        const float4 v0 = *reinterpret_cast<const float4*>(src);
        const float4 v1 = *reinterpret_cast<const float4*>(src + 4);
        f16x8 h, l;
        h[0] = (_Float16)v0.x; l[0] = (_Float16)((v0.x - (float)h[0]) * 4096.0f);
        h[1] = (_Float16)v0.y; l[1] = (_Float16)((v0.y - (float)h[1]) * 4096.0f);
        h[2] = (_Float16)v0.z; l[2] = (_Float16)((v0.z - (float)h[2]) * 4096.0f);
        h[3] = (_Float16)v0.w; l[3] = (_Float16)((v0.w - (float)h[3]) * 4096.0f);
        h[4] = (_Float16)v1.x; l[4] = (_Float16)((v1.x - (float)h[4]) * 4096.0f);
        h[5] = (_Float16)v1.y; l[5] = (_Float16)((v1.y - (float)h[5]) * 4096.0f);
        h[6] = (_Float16)v1.z; l[6] = (_Float16)((v1.z - (float)h[6]) * 4096.0f);
        h[7] = (_Float16)v1.w; l[7] = (_Float16)((v1.w - (float)h[7]) * 4096.0f);
        *reinterpret_cast<f16x8*>(&ldsA[bf][0][sr][po]) = h;
        *reinterpret_cast<f16x8*>(&ldsA[bf][1][sr][po]) = l;
        gload16(wh + (size_t)(col0 + sr) * DIN + k0 + kq, &ldsB[bf][0][sr][kq]);
        gload16(wl + (size_t)(col0 + sr) * DIN + k0 + kq, &ldsB[bf][1][sr][kq]);
    };

    stage(0, 0);

    int buf = 0;
    for (int kt = 0; kt < 16; ++kt) {
        __syncthreads();   // stage(kt) resident (vm+lgkm); prior reads done
        if (kt < 15) stage(buf ^ 1, (kt + 1) * 32);

        f16x8 ah[4], al[4];
#pragma unroll
        for (int fr = 0; fr < 4; ++fr) {
            ah[fr] = *reinterpret_cast<const f16x8*>(&ldsA[buf][0][wr + fr * 16 + lrow][gsw]);
            al[fr] = *reinterpret_cast<const f16x8*>(&ldsA[buf][1][wr + fr * 16 + lrow][gsw]);
        }
#pragma unroll
        for (int fc = 0; fc < 2; ++fc) {
            const f16x8 bh = *reinterpret_cast<const f16x8*>(&ldsB[buf][0][wc + fc * 16 + lrow][gsw]);
            const f16x8 bl = *reinterpret_cast<const f16x8*>(&ldsB[buf][1][wc + fc * 16 + lrow][gsw]);
#pragma unroll
            for (int fr = 0; fr < 4; ++fr) {
                acc_hh[fr][fc] = __builtin_amdgcn_mfma_f32_16x16x32_f16(ah[fr], bh, acc_hh[fr][fc], 0, 0, 0);
                acc_cr[fr][fc] = __builtin_amdgcn_mfma_f32_16x16x32_f16(ah[fr], bl, acc_cr[fr][fc], 0, 0, 0);
                acc_cr[fr][fc] = __builtin_amdgcn_mfma_f32_16x16x32_f16(al[fr], bh, acc_cr[fr][fc], 0, 0, 0);
            }
        }
        buf ^= 1;
    }

    // epilogue: cur = hh + 2^-12 * cross + bias (C/D: col=lane&15, row=(lane>>4)*4+reg)
#pragma unroll
    for (int fr = 0; fr < 4; ++fr)
#pragma unroll
        for (int fc = 0; fc < 2; ++fc) {
            const int col = col0 + wc + fc * 16 + lrow;
            const float bv = bias[col];
#pragma unroll
            for (int r = 0; r < 4; ++r) {
                const int row = row0 + wr + fr * 16 + (lane >> 4) * 4 + r;
                C[(size_t)row * DH + col] =
                    acc_hh[fr][fc][r] + acc_cr[fr][fc][r] * (1.0f / 4096.0f) + bv;
            }
        }
}

// ========== Pass 3: scan + flag, 1 chain/thread + nt stores =================
// Per-element step arithmetic identical to R4-R18 (contract off, same order).
__global__ __launch_bounds__(256) void snn_scan_flag(float* __restrict__ buf,
                                                     float* __restrict__ spk,
                                                     unsigned* __restrict__ cnt_b,
                                                     unsigned* __restrict__ list_b) {
#pragma clang fp contract(off)
    const int i = blockIdx.x * 256 + threadIdx.x;
    float c[8];
#pragma unroll
    for (int t = 0; t < 8; ++t) c[t] = buf[(size_t)t * BH + i];
    float mem = 0.0f;
    bool flag = false;
#pragma unroll 8
    for (int t = 0; t < T_STEPS - 8; ++t) {
        const float cur = c[t & 7];
        c[t & 7] = buf[(size_t)(t + 8) * BH + i];   // 8 loads in flight
        const float reset = (mem > 1.0f) ? 1.0f : 0.0f;
        float tmp = 0.9f * mem;
        tmp = tmp + cur;
        mem = tmp - reset;
        flag = flag || (fabsf(mem - 1.0f) < MARGIN);
        const float s = (mem > 1.0f) ? 1.0f : 0.0f;
        __builtin_nontemporal_store(s, &spk[(size_t)t * BH + i]);
        __builtin_nontemporal_store(mem, &buf[(size_t)t * BH + i]);
    }
#pragma unroll
    for (int t = T_STEPS - 8; t < T_STEPS; ++t) {
        const float cur = c[t & 7];
        const float reset = (mem > 1.0f) ? 1.0f : 0.0f;
        float tmp = 0.9f * mem;
        tmp = tmp + cur;
        mem = tmp - reset;
        flag = flag || (fabsf(mem - 1.0f) < MARGIN);
        const float s = (mem > 1.0f) ? 1.0f : 0.0f;
        __builtin_nontemporal_store(s, &spk[(size_t)t * BH + i]);
        __builtin_nontemporal_store(mem, &buf[(size_t)t * BH + i]);
    }
    if (flag) {
        const int b = i >> 9;         // i = b*512 + h
        const int h = i & 511;
        const unsigned slot = atomicAdd(&cnt_b[b], 1u);
        if (slot < (unsigned)LISTCAP) list_b[(size_t)b * LISTCAP + slot] = (unsigned)h;
    }
}

// ======== Pass 4: exact dot recompute — R14 (8 t x 8 slots per wave) ========
__global__ __launch_bounds__(256) void exact_cur_g(const float* __restrict__ x,
                                                   const float* __restrict__ W,
                                                   const float* __restrict__ bias,
                                                   const unsigned* __restrict__ cnt_b,
                                                   const unsigned* __restrict__ list_b,
                                                   float* __restrict__ cur_ex) {
    const int b = blockIdx.x;
    unsigned n = cnt_b[b];
    if (n == 0) return;
    const bool all = (n > (unsigned)LISTCAP);
    if (all) n = 512;

    const int jl = (int)(threadIdx.x & 7);        // slot within group of 8
    const int tl = (int)(threadIdx.x >> 3);       // 0..31
    const int t  = blockIdx.y * TQ2 + tl;
    if (t >= T_STEPS) return;                     // no barriers in kernel
    const float4* xr = reinterpret_cast<const float4*>(x + ((size_t)t * BATCH + b) * DIN);

    for (unsigned base = 0; base < n; base += 8) {
        const unsigned slot = base + (unsigned)jl;
        if (slot >= n) break;
        const int h = all ? (int)slot : (int)list_b[(size_t)b * LISTCAP + slot];
        const float4* wr = reinterpret_cast<const float4*>(W + (size_t)h * DIN);
        float acc = 0.0f;
#pragma unroll 8
        for (int kk = 0; kk < DIN / 4; ++kk) {   // ascending-k fma chain == np
            const float4 a = xr[kk];
            const float4 ww = wr[kk];
            acc = fmaf(a.x, ww.x, acc);
            acc = fmaf(a.y, ww.y, acc);
            acc = fmaf(a.z, ww.z, acc);
            acc = fmaf(a.w, ww.w, acc);
        }
        cur_ex[((size_t)b * 512 + slot) * T_STEPS + t] = acc + bias[h];
    }
}

// ======== Pass 5: exact rescan, one THREAD per flagged pair =================
__global__ __launch_bounds__(256) void rescan_g(const float* __restrict__ cur_ex,
                                                const unsigned* __restrict__ cnt_b,
                                                const unsigned* __restrict__ list_b,
                                                float* __restrict__ buf,
                                                float* __restrict__ spk) {
#pragma clang fp contract(off)
    const int b = blockIdx.x;
    unsigned n = cnt_b[b];
    if (n == 0) return;
    const bool all = (n > (unsigned)LISTCAP);
    if (all) n = 512;

    for (unsigned slot = threadIdx.x; slot < n; slot += 256) {
        const int h = all ? (int)slot : (int)list_b[(size_t)b * LISTCAP + slot];
        const unsigned i = ((unsigned)b << 9) | (unsigned)h;
        const float* cr = cur_ex + ((size_t)b * 512 + slot) * T_STEPS;
        float mem = 0.0f;
        for (int t = 0; t < T_STEPS; ++t) {
            const float c = cr[t];
            const float reset = (mem > 1.0f) ? 1.0f : 0.0f;
            float tmp = 0.9f * mem;
            tmp = tmp + c;
            mem = tmp - reset;
            const float s = (mem > 1.0f) ? 1.0f : 0.0f;
            spk[(size_t)t * BH + i] = s;
            buf[(size_t)t * BH + i] = mem;
        }
    }
}

// ================= legacy f32 path (R3, verified absmax 0.0) ================
#define BKf 32
#define LPADf 132
__global__ __launch_bounds__(256, 3) void gemm_nt_f32(const float* __restrict__ A,
                                                      const float* __restrict__ W,
                                                      const float* __restrict__ bias,
                                                      float* __restrict__ C) {
    __shared__ float As[BKf][LPADf];
    __shared__ float Bs[BKf][LPADf];
    const int tid = threadIdx.x;
    const int tx = tid & 15, ty = tid >> 4;
    const int row0 = blockIdx.x * 128, col0 = blockIdx.y * 128;
    const int lr = tid >> 2, lk = (tid & 3) * 4;
    const float* Abase = A + (size_t)(row0 + lr) * DIN + lk;
    const float* Bbase = W + (size_t)(col0 + lr) * DIN + lk;
    float acc[8][8] = {};
    float4 ra00, ra01, ra10, ra11, rb00, rb01, rb10, rb11;
#define LOADREG(k0)                                                        \
    do {                                                                   \
        ra00 = *reinterpret_cast<const float4*>(Abase + (k0));             \
        ra01 = *reinterpret_cast<const float4*>(Abase + (k0) + 16);        \
        ra10 = *reinterpret_cast<const float4*>(Abase + 64 * DIN + (k0));  \
        ra11 = *reinterpret_cast<const float4*>(Abase + 64 * DIN + (k0) + 16); \
        rb00 = *reinterpret_cast<const float4*>(Bbase + (k0));             \
        rb01 = *reinterpret_cast<const float4*>(Bbase + (k0) + 16);        \
        rb10 = *reinterpret_cast<const float4*>(Bbase + 64 * DIN + (k0));  \
        rb11 = *reinterpret_cast<const float4*>(Bbase + 64 * DIN + (k0) + 16); \
    } while (0)
#define STOREV(arr, kb, r, v)                                              \
    do { arr[(kb)+0][r]=(v).x; arr[(kb)+1][r]=(v).y; arr[(kb)+2][r]=(v).z; arr[(kb)+3][r]=(v).w; } while (0)
    LOADREG(0);
    for (int kt = 0; kt < DIN / BKf; ++kt) {
        __syncthreads();
        STOREV(As, lk, lr, ra00); STOREV(As, 16 + lk, lr, ra01);
        STOREV(As, lk, lr + 64, ra10); STOREV(As, 16 + lk, lr + 64, ra11);
        STOREV(Bs, lk, lr, rb00); STOREV(Bs, 16 + lk, lr, rb01);
        STOREV(Bs, lk, lr + 64, rb10); STOREV(Bs, 16 + lk, lr + 64, rb11);
        __syncthreads();
        if (kt + 1 < DIN / BKf) LOADREG((kt + 1) * BKf);
#pragma unroll 8
        for (int k = 0; k < BKf; ++k) {
            float a[8], b[8];
            const float4 t0 = *reinterpret_cast<const float4*>(&As[k][ty * 8 + 0]);
            const float4 t1 = *reinterpret_cast<const float4*>(&As[k][ty * 8 + 4]);
            a[0]=t0.x; a[1]=t0.y; a[2]=t0.z; a[3]=t0.w;
            a[4]=t1.x; a[5]=t1.y; a[6]=t1.z; a[7]=t1.w;
            const float4 u0 = *reinterpret_cast<const float4*>(&Bs[k][tx * 4]);
            const float4 u1 = *reinterpret_cast<const float4*>(&Bs[k][64 + tx * 4]);
            b[0]=u0.x; b[1]=u0.y; b[2]=u0.z; b[3]=u0.w;
            b[4]=u1.x; b[5]=u1.y; b[6]=u1.z; b[7]=u1.w;
#pragma unroll
            for (int i = 0; i < 8; ++i)
#pragma unroll
                for (int j = 0; j < 8; ++j) acc[i][j] += a[i] * b[j];
        }
    }
#pragma unroll
    for (int i = 0; i < 8; ++i) {
        const int r = row0 + ty * 8 + i, c0 = col0 + tx * 4, c1 = col0 + 64 + tx * 4;
        float4 o0, o1;
        o0.x = acc[i][0] + bias[c0 + 0]; o0.y = acc[i][1] + bias[c0 + 1];
        o0.z = acc[i][2] + bias[c0 + 2]; o0.w = acc[i][3] + bias[c0 + 3];
        o1.x = acc[i][4] + bias[c1 + 0]; o1.y = acc[i][5] + bias[c1 + 1];
        o1.z = acc[i][6] + bias[c1 + 2]; o1.w = acc[i][7] + bias[c1 + 3];
        *reinterpret_cast<float4*>(&C[(size_t)r * DH + c0]) = o0;
        *reinterpret_cast<float4*>(&C[(size_t)r * DH + c1]) = o1;
    }
#undef LOADREG
#undef STOREV
}

__global__ __launch_bounds__(256) void snn_scan(float* buf, float* spk) {
    const int i = blockIdx.x * 256 + threadIdx.x;
    float mem = 0.0f;
    float c = buf[i];
    for (int t = 0; t < T_STEPS; ++t) {
        float cn = (t + 1 < T_STEPS) ? buf[(size_t)(t + 1) * BH + i] : 0.0f;
        const float reset = (mem > 1.0f) ? 1.0f : 0.0f;
        mem = 0.9f * mem + c - reset;
        const float s = (mem > 1.0f) ? 1.0f : 0.0f;
        spk[(size_t)t * BH + i] = s;
        buf[(size_t)t * BH + i] = mem;
        c = cn;
    }
}

// ============================================================================
extern "C" void kernel_launch(void* const* d_in, const int* in_sizes, int n_in,
                              void* d_out, int out_size, void* d_ws, size_t ws_size,
                              hipStream_t stream) {
    const float* x    = (const float*)d_in[0];
    const float* W    = (const float*)d_in[1];
    const float* bias = (const float*)d_in[2];
    float* out = (float*)d_out;
    float* spk = out;
    float* mem = out + TBH;   // holds cur between GEMM and scan

    if (ws_size >= WS_REQ) {
        char* ws = (char*)d_ws;
        _Float16* wh = (_Float16*)(ws + OFF_WH);
        _Float16* wl = (_Float16*)(ws + OFF_WL);
        unsigned* cnt_b  = (unsigned*)(ws + OFF_CNTB);
        unsigned* list_b = (unsigned*)(ws + OFF_LISTB);
        float*    cur_ex = (float*)ws;   // [0, 104.9MB): free until Pass 4

        (void)hipMemsetAsync(cnt_b, 0, 1024, stream);
        convert_w<<<256, 256, 0, stream>>>(W, wh, wl);
        gemm_split<<<1600, 512, 0, stream>>>(x, wh, wl, bias, mem);
        snn_scan_flag<<<BH / 256, 256, 0, stream>>>(mem, spk, cnt_b, list_b);
        dim3 egrid(BATCH, (T_STEPS + TQ2 - 1) / TQ2);  // 256 x 7
        exact_cur_g<<<egrid, 256, 0, stream>>>(x, W, bias, cnt_b, list_b, cur_ex);
        rescan_g<<<BATCH, 256, 0, stream>>>(cur_ex, cnt_b, list_b, mem, spk);
    } else {
        dim3 grid(MM / 128, DH / 128);
        gemm_nt_f32<<<grid, 256, 0, stream>>>(x, W, bias, mem);
        snn_scan<<<BH / 256, 256, 0, stream>>>(mem, spk);
    }
}